// Round 3
// baseline (164.357 us; speedup 1.0000x reference)
//
#include <hip/hip_runtime.h>
#include <hip/hip_bf16.h>

typedef __bf16    bf16x8 __attribute__((ext_vector_type(8)));
typedef __bf16    bf16x4 __attribute__((ext_vector_type(4)));
typedef _Float16  f16x8  __attribute__((ext_vector_type(8)));
typedef _Float16  f16x4  __attribute__((ext_vector_type(4)));
typedef float     f32x4  __attribute__((ext_vector_type(4)));

#define HL 50
#define DD 64

// ============================ ALGORITHM =================================
// h1 = relu(A2[va] + F2[af] + ba[node]) with A2 = f16(a2e@W1[0:64]),
// F2 = f16(f2e@W1[128:192]), ba = f16(b1 + rep@W1[64:128]).  E16 = f16(a2e)
// feeds the output weighted sum.  All derived tables f16.
// R10: prep A/F branch = GRID-STRIDE PIPELINED tiles (448 blocks/table,
// ~3.5 tiles each, one barrier total, next-tile loads in flight during
// current MFMA).  Main = R8 wave-per-node (E16 prefetch REVERTED — it cost
// +13us via VGPR/occupancy) with launch_bounds(256,6) for 24 waves/CU.

// ---- fused prep: [0,GAF) A-tiles | [GAF,2GAF) F-tiles | bias | frags
__global__ __launch_bounds__(256, 4) void prep_all_kernel(
    const int*   __restrict__ nodes,
    const float* __restrict__ v2e,
    const float* __restrict__ a2e,
    const float* __restrict__ f2e,
    const float* __restrict__ W1,
    const float* __restrict__ b1,
    const float* __restrict__ W2,
    const float* __restrict__ b2,
    const float* __restrict__ w3,
    _Float16* __restrict__ A2, _Float16* __restrict__ F2,
    _Float16* __restrict__ E16, _Float16* __restrict__ ba16,
    _Float16* __restrict__ w2f, float* __restrict__ wsc,
    int nA, int nF, int N, int GAF, int GB)
{
    __shared__ __align__(16) _Float16 wlds[8 * 512];  // 8192 B: W1-part fragments
    __shared__ __align__(16) _Float16 es[64 * 72];    // 9216 B
    const int tid  = threadIdx.x;
    const int w    = tid >> 6, lane = tid & 63;
    const int lq   = lane & 15, quad = lane >> 4;
    const int bid  = blockIdx.x;

    if (bid < 2 * GAF) {
        // ==== embed transform: grid-stride tiles, pipelined, ONE barrier ====
        const bool  isA   = (bid < GAF);
        const int   t0    = isA ? bid : bid - GAF;
        const int   nrows = isA ? nA : nF;
        const int   NT    = (nrows + 63) >> 6;
        const float* src  = isA ? a2e : f2e;
        const float* Wp   = isA ? W1 : (W1 + 128 * DD);
        _Float16*   dst   = isA ? A2 : F2;
        _Float16*   ws_   = &es[w * 16 * 72];          // wave-private slice

        // tile loader: 16 rows/wave as 4x float4 per lane
        auto loadtile = [&](int tb, float4 (&vv)[4], int (&gg)[4]) {
            const int r0w = tb * 64 + w * 16;
            #pragma unroll
            for (int i = 0; i < 4; ++i) {
                int t = i * 64 + lane;
                int row = t >> 4, chunk = t & 15;
                int gr = r0w + row; if (gr >= nrows) gr = nrows - 1;
                gg[i] = gr;
                vv[i] = *(const float4*)(src + (size_t)gr * DD + chunk * 4);
            }
        };

        // stage W1-part into LDS in fragment layout (L2-hot reads)
        #pragma unroll
        for (int h = 0; h < 2; ++h) {
            int combo = w + 4 * h;            // = ct*2 + t, combos 0..7
            int ct = combo >> 1, t = combo & 1;
            f16x8 pk;
            #pragma unroll
            for (int j = 0; j < 8; ++j)
                pk[j] = (_Float16)Wp[(t * 32 + quad * 8 + j) * DD + ct * 16 + lq];
            *(f16x8*)&wlds[(size_t)combo * 512 + lane * 8] = pk;
        }

        // prologue: first tile's loads in flight across the barrier
        int    tb = t0;
        float4 v[4];
        int    grv[4];
        loadtile(tb, v, grv);

        __syncthreads();   // [only barrier] wlds ready; ws_ is wave-private

        for (;;) {
            const int r0w = tb * 64 + w * 16;

            // cvt current tile -> wave-private LDS (+ free E16 copy)
            #pragma unroll
            for (int i = 0; i < 4; ++i) {
                int t = i * 64 + lane;
                int row = t >> 4, chunk = t & 15;
                f16x4 pk = {(_Float16)v[i].x, (_Float16)v[i].y,
                            (_Float16)v[i].z, (_Float16)v[i].w};
                *(f16x4*)&ws_[row * 72 + chunk * 4] = pk;
                if (isA) *(f16x4*)(E16 + (size_t)grv[i] * DD + chunk * 4) = pk;
            }

            // issue NEXT tile's global loads (hide HBM under MFMA below)
            const int tn = tb + GAF;
            float4 vn[4];
            int    grn[4];
            if (tn < NT) loadtile(tn, vn, grn);

            // fragments + 8 MFMA (4 col-tiles x 2 K-steps), wave-local
            f16x8 afr[2];
            #pragma unroll
            for (int t = 0; t < 2; ++t)
                afr[t] = *(const f16x8*)&ws_[lq * 72 + t * 32 + quad * 8];
            f32x4 acc[4];
            #pragma unroll
            for (int ct = 0; ct < 4; ++ct) {
                acc[ct] = (f32x4){0.f, 0.f, 0.f, 0.f};
                #pragma unroll
                for (int t = 0; t < 2; ++t) {
                    f16x8 bfr = *(const f16x8*)&wlds[(size_t)(ct * 2 + t) * 512 + lane * 8];
                    acc[ct] = __builtin_amdgcn_mfma_f32_16x16x32_f16(afr[t], bfr, acc[ct], 0, 0, 0);
                }
            }

            // repack via wave-private LDS, then vectorized global store
            #pragma unroll
            for (int ct = 0; ct < 4; ++ct)
                #pragma unroll
                for (int r = 0; r < 4; ++r)
                    ws_[(quad * 4 + r) * 72 + ct * 16 + lq] = (_Float16)acc[ct][r];
            {
                int row = lane >> 2, g = lane & 3;
                int gr  = r0w + row;
                if (gr < nrows) {
                    f16x8 v0 = *(const f16x8*)&ws_[row * 72 + g * 16];
                    f16x8 v1 = *(const f16x8*)&ws_[row * 72 + g * 16 + 8];
                    *(f16x8*)(dst + (size_t)gr * DD + g * 16)     = v0;
                    *(f16x8*)(dst + (size_t)gr * DD + g * 16 + 8) = v1;
                }
            }

            if (tn >= NT) break;
            tb = tn;
            #pragma unroll
            for (int i = 0; i < 4; ++i) { v[i] = vn[i]; grv[i] = grn[i]; }
        }
    } else if (bid < 2 * GAF + GB) {
        // ---- bias branch: ba16[n][c] = f16(b1[c] + rep_n . W1[64:128, c]) ----
        const int col = w * 16 + lq;
        const int n0 = (bid - 2 * GAF) * 64;
        #pragma unroll
        for (int i = 0; i < 4; ++i) {
            int t = i * 256 + tid;
            int row = t >> 4, q = t & 15;
            int gn = n0 + row; if (gn >= N) gn = N - 1;
            int idx = nodes[gn];
            float4 v = *(const float4*)(v2e + (size_t)idx * DD + q * 4);
            f16x4 pk = {(_Float16)v.x, (_Float16)v.y, (_Float16)v.z, (_Float16)v.w};
            *(f16x4*)&es[row * 72 + q * 4] = pk;
        }
        f16x8 bfr[2];
        #pragma unroll
        for (int t = 0; t < 2; ++t)
            #pragma unroll
            for (int j = 0; j < 8; ++j)
                bfr[t][j] = (_Float16)W1[(64 + t * 32 + quad * 8 + j) * DD + col];
        const float b1c = b1[col];
        __syncthreads();

        f32x4 acc[4];
        #pragma unroll
        for (int mt = 0; mt < 4; ++mt) acc[mt] = (f32x4){0.f, 0.f, 0.f, 0.f};
        #pragma unroll
        for (int t = 0; t < 2; ++t)
            #pragma unroll
            for (int mt = 0; mt < 4; ++mt) {
                f16x8 a = *(const f16x8*)&es[(mt * 16 + lq) * 72 + t * 32 + quad * 8];
                acc[mt] = __builtin_amdgcn_mfma_f32_16x16x32_f16(a, bfr[t], acc[mt], 0, 0, 0);
            }
        #pragma unroll
        for (int mt = 0; mt < 4; ++mt)
            #pragma unroll
            for (int r = 0; r < 4; ++r) {
                int gn = n0 + mt * 16 + quad * 4 + r;
                if (gn < N) ba16[(size_t)gn * DD + col] = (_Float16)(acc[mt][r] + b1c);
            }
    } else {
        // ---- frag branch: W2 B-fragments (f16) + scalars ----
        const int ln = tid & 63, c0 = tid >> 6;
        #pragma unroll
        for (int h = 0; h < 2; ++h) {
            int combo = c0 + 4 * h;          // = ct*2 + t
            int ct = combo >> 1, t = combo & 1;
            _Float16* d = w2f + ((size_t)combo * 64 + ln) * 8;
            #pragma unroll
            for (int j = 0; j < 8; ++j)
                d[j] = (_Float16)W2[(t * 32 + (ln >> 4) * 8 + j) * DD + ct * 16 + (ln & 15)];
        }
        if (tid < 64) { wsc[tid] = w3[tid]; wsc[64 + tid] = b2[tid]; }
    }
}

// ---- main: ONE NODE PER WAVE — no barriers, no LDS, in-register softmax ----
__global__ __launch_bounds__(256, 6) void va_main_kernel(
    const int*      __restrict__ hva,
    const int*      __restrict__ haf,
    const _Float16* __restrict__ A2,
    const _Float16* __restrict__ F2,
    const _Float16* __restrict__ E16,
    const _Float16* __restrict__ ba16,
    const _Float16* __restrict__ w2f,
    const float*    __restrict__ wsc,
    float*          __restrict__ out, int Ntot)
{
    const int tid  = threadIdx.x;
    const int w    = tid >> 6;
    const int lane = tid & 63;
    const int lq   = lane & 15;
    const int quad = lane >> 4;
    const int node = blockIdx.x * 4 + w;
    if (node >= Ntot) return;

    const int* hb = hva + node * HL;
    const int* fb = haf + node * HL;
    const int lclamp = (lane < HL) ? lane : 0;
    const int iv  = hb[lclamp];                 // lane l holds hva[l]
    const int ifv = fb[lclamp];                 // lane l holds haf[l]

    // ---- node-uniform bias fragments ----
    f16x8 bag[2];
    #pragma unroll
    for (int t = 0; t < 2; ++t)
        bag[t] = *(const f16x8*)(ba16 + (size_t)node * DD + t * 32 + quad * 8);

    // ---- gather A2/F2 fragments for all 4 row-tiles (loads issued early) ----
    f16x8 a2g[4][2], f2g[4][2];
    #pragma unroll
    for (int mt = 0; mt < 4; ++mt) {
        const int row = mt * 16 + lq;
        const int ia  = __shfl(iv,  row);
        const int ifm = __shfl(ifv, row);
        const bool valid = (row < HL);          // compile-time true for mt<3
        #pragma unroll
        for (int t = 0; t < 2; ++t) {
            if (valid) {
                a2g[mt][t] = *(const f16x8*)(A2 + (size_t)ia  * DD + t * 32 + quad * 8);
                f2g[mt][t] = *(const f16x8*)(F2 + (size_t)ifm * DD + t * 32 + quad * 8);
            }
        }
    }

    // ---- h1 = relu(A2 + F2 + ba), invalid rows forced to 0 ----
    f16x8 h1f[4][2];
    #pragma unroll
    for (int mt = 0; mt < 4; ++mt) {
        const bool valid = (mt * 16 + lq) < HL;
        #pragma unroll
        for (int t = 0; t < 2; ++t) {
            f16x8 h = a2g[mt][t] + f2g[mt][t] + bag[t];
            #pragma unroll
            for (int j = 0; j < 8; ++j)
                h1f[mt][t][j] = (valid && h[j] > (_Float16)0.f) ? h[j] : (_Float16)0.f;
        }
    }

    // ---- GEMM2 (4 row-tiles x 4 col-tiles x 2 K) + score partials ----
    float sc[4][4];
    #pragma unroll
    for (int mt = 0; mt < 4; ++mt)
        #pragma unroll
        for (int r = 0; r < 4; ++r) sc[mt][r] = 0.f;

    #pragma unroll
    for (int ct = 0; ct < 4; ++ct) {
        const float b2c = wsc[64 + ct * 16 + lq];
        const float w3c = wsc[ct * 16 + lq];
        f16x8 bfr[2];
        #pragma unroll
        for (int t = 0; t < 2; ++t)
            bfr[t] = *(const f16x8*)(w2f + ((size_t)(ct * 2 + t) * 64 + lane) * 8);
        #pragma unroll
        for (int mt = 0; mt < 4; ++mt) {
            f32x4 acc = {b2c, b2c, b2c, b2c};
            #pragma unroll
            for (int t = 0; t < 2; ++t)
                acc = __builtin_amdgcn_mfma_f32_16x16x32_f16(h1f[mt][t], bfr[t], acc, 0, 0, 0);
            #pragma unroll
            for (int r = 0; r < 4; ++r)
                sc[mt][r] = fmaf(fmaxf(acc[r], 0.f), w3c, sc[mt][r]);
        }
    }

    // ---- reduce scores over lq (each lane then holds its quad's 16 rows) ----
    #pragma unroll
    for (int mt = 0; mt < 4; ++mt)
        #pragma unroll
        for (int r = 0; r < 4; ++r)
            #pragma unroll
            for (int m = 1; m < 16; m <<= 1)
                sc[mt][r] += __shfl_xor(sc[mt][r], m);

    // ---- in-register softmax over 50 rows (row = mt*16 + quad*4 + r) ----
    #pragma unroll
    for (int r = 0; r < 4; ++r)
        if (48 + quad * 4 + r >= HL) sc[3][r] = -3.0e38f;   // rows 50..63

    float mx = sc[0][0];
    #pragma unroll
    for (int mt = 0; mt < 4; ++mt)
        #pragma unroll
        for (int r = 0; r < 4; ++r) mx = fmaxf(mx, sc[mt][r]);
    mx = fmaxf(mx, __shfl_xor(mx, 16));
    mx = fmaxf(mx, __shfl_xor(mx, 32));

    float sm = 0.f;
    #pragma unroll
    for (int mt = 0; mt < 4; ++mt)
        #pragma unroll
        for (int r = 0; r < 4; ++r) {
            sc[mt][r] = __expf(sc[mt][r] - mx);             // 0 for invalid rows
            sm += sc[mt][r];
        }
    sm += __shfl_xor(sm, 16);
    sm += __shfl_xor(sm, 32);
    const float inv = 1.f / sm;

    // ---- weighted e_va sum: post-softmax gather (R1 proven form) ----
    float oa[4] = {0.f, 0.f, 0.f, 0.f};
    #pragma unroll
    for (int l = 0; l < HL; ++l) {
        const int   srcl = ((l >> 2) & 3) << 4;             // lane with quad=(l>>2)&3
        const float av   = __shfl(sc[l >> 4][l & 3], srcl);
        const int   idx  = __builtin_amdgcn_readlane(iv, l); // wave-uniform -> SGPR base
        oa[l & 3] = fmaf(av, (float)E16[(size_t)idx * DD + lane], oa[l & 3]);
    }
    out[(size_t)node * DD + lane] = ((oa[0] + oa[1]) + (oa[2] + oa[3])) * inv;
}

// ======================= FALLBACK (proven R6 path) ======================
#define FMR  112
#define FMT  7
#define FXSS 136

__global__ __launch_bounds__(256) void fb_prep_kernel(
    const float* __restrict__ W1, const float* __restrict__ W2,
    const float* __restrict__ w3, const float* __restrict__ b1,
    const float* __restrict__ b2,
    __bf16* __restrict__ wf, float* __restrict__ wsc)
{
    const int tid  = threadIdx.x;
    const int quad = tid >> 6;
    const int col  = tid & 63;
    __bf16* dst = wf + tid * 64;
    #pragma unroll
    for (int t = 0; t < 4; ++t)
        #pragma unroll
        for (int j = 0; j < 8; ++j) {
            int keff = t * 32 + quad * 8 + j;
            int krow = (keff < 64) ? keff : keff + 64;
            dst[t * 8 + j] = (__bf16)W1[krow * 64 + col];
        }
    #pragma unroll
    for (int t = 0; t < 2; ++t)
        #pragma unroll
        for (int j = 0; j < 8; ++j) {
            dst[32 + t * 8 + j] = (__bf16)W1[(64 + t * 32 + quad * 8 + j) * 64 + col];
            dst[48 + t * 8 + j] = (__bf16)W2[(t * 32 + quad * 8 + j) * 64 + col];
        }
    if (tid < 64) {
        wsc[tid] = w3[tid]; wsc[64 + tid] = b1[tid]; wsc[128 + tid] = b2[tid];
    }
}

__global__ __launch_bounds__(256, 5) void fb_agg_kernel(
    const int* __restrict__ nodes, const int* __restrict__ hva,
    const int* __restrict__ haf, const float* __restrict__ v2e,
    const float* __restrict__ a2e, const float* __restrict__ f2e,
    const __bf16* __restrict__ wf, const float* __restrict__ wsc,
    float* __restrict__ out)
{
    __shared__ __bf16 xs[FMR * FXSS];
    __shared__ float  pbuf[4 * FMR];
    const int tid = threadIdx.x;
    const int w = tid >> 6, lane = tid & 63, lq = lane & 15, quad = lane >> 4;
    const int col = w * 16 + lq;
    const int n0 = blockIdx.x * 2;
    {
        const int* hb = hva + n0 * HL;
        const int* fb = haf + n0 * HL;
        #pragma unroll
        for (int i = 0; i < 13; ++i) {
            int t = i * 256 + tid;
            if (t < 2 * HL * 2 * 16) {
                int r = t >> 4, q = t & 15;
                bool va = (r < 2 * HL);
                int gr = va ? r : r - 2 * HL;
                int idx = va ? hb[gr] : fb[gr];
                const float* src = (va ? a2e : f2e) + (size_t)idx * DD + q * 4;
                float4 v = *(const float4*)src;
                bf16x4 pk = {(__bf16)v.x, (__bf16)v.y, (__bf16)v.z, (__bf16)v.w};
                *(bf16x4*)&xs[gr * FXSS + (va ? 0 : DD) + q * 4] = pk;
            }
        }
    }
    bf16x8 repf[2];
    #pragma unroll
    for (int t = 0; t < 2; ++t)
        #pragma unroll
        for (int j = 0; j < 8; ++j) repf[t][j] = (__bf16)0.f;
    if (lq < 2) {
        int nd = nodes[n0 + lq];
        const float* rp = v2e + (size_t)nd * DD;
        #pragma unroll
        for (int t = 0; t < 2; ++t) {
            float4 v0 = *(const float4*)(rp + t * 32 + quad * 8);
            float4 v1 = *(const float4*)(rp + t * 32 + quad * 8 + 4);
            repf[t] = (bf16x8){(__bf16)v0.x, (__bf16)v0.y, (__bf16)v0.z, (__bf16)v0.w,
                               (__bf16)v1.x, (__bf16)v1.y, (__bf16)v1.z, (__bf16)v1.w};
        }
    }
    const __bf16* fbp = wf + (size_t)(quad * 64 + col) * 64;
    bf16x8 b1f[4], b1u[2], b2f[2];
    #pragma unroll
    for (int t = 0; t < 4; ++t) b1f[t] = *(const bf16x8*)(fbp + t * 8);
    #pragma unroll
    for (int t = 0; t < 2; ++t) {
        b1u[t] = *(const bf16x8*)(fbp + 32 + t * 8);
        b2f[t] = *(const bf16x8*)(fbp + 48 + t * 8);
    }
    const float w3c = wsc[col];
    const float b1c = wsc[64 + col];
    const float b2c = wsc[128 + col];
    f32x4 rb = {0.f, 0.f, 0.f, 0.f};
    #pragma unroll
    for (int t = 0; t < 2; ++t)
        rb = __builtin_amdgcn_mfma_f32_16x16x32_bf16(repf[t], b1u[t], rb, 0, 0, 0);
    const float bias0 = __shfl(rb[0], lq) + b1c;
    const float bias1 = __shfl(rb[1], lq) + b1c;
    __syncthreads();
    f32x4 acc[FMT];
    #pragma unroll
    for (int mt = 0; mt < FMT; ++mt)
        #pragma unroll
        for (int r = 0; r < 4; ++r) {
            int gr = mt * 16 + quad * 4 + r;
            acc[mt][r] = (gr >= HL) ? bias1 : bias0;
        }
    #pragma unroll
    for (int t = 0; t < 4; ++t)
        #pragma unroll
        for (int mt = 0; mt < FMT; ++mt) {
            bf16x8 a = *(const bf16x8*)&xs[(mt * 16 + lq) * FXSS + t * 32 + quad * 8];
            acc[mt] = __builtin_amdgcn_mfma_f32_16x16x32_bf16(a, b1f[t], acc[mt], 0, 0, 0);
        }
    __syncthreads();
    #pragma unroll
    for (int mt = 0; mt < FMT; ++mt)
        #pragma unroll
        for (int r = 0; r < 4; ++r) {
            int gr = mt * 16 + quad * 4 + r;
            xs[gr * FXSS + DD + col] = (__bf16)fmaxf(acc[mt][r], 0.f);
        }
    __syncthreads();
    f32x4 a2[FMT];
    #pragma unroll
    for (int mt = 0; mt < FMT; ++mt) a2[mt] = (f32x4){b2c, b2c, b2c, b2c};
    #pragma unroll
    for (int t = 0; t < 2; ++t)
        #pragma unroll
        for (int mt = 0; mt < FMT; ++mt) {
            bf16x8 a = *(const bf16x8*)&xs[(mt * 16 + lq) * FXSS + DD + t * 32 + quad * 8];
            a2[mt] = __builtin_amdgcn_mfma_f32_16x16x32_bf16(a, b2f[t], a2[mt], 0, 0, 0);
        }
    #pragma unroll
    for (int mt = 0; mt < FMT; ++mt) {
        float p0 = fmaxf(a2[mt][0], 0.f) * w3c;
        float p1 = fmaxf(a2[mt][1], 0.f) * w3c;
        float p2 = fmaxf(a2[mt][2], 0.f) * w3c;
        float p3 = fmaxf(a2[mt][3], 0.f) * w3c;
        #pragma unroll
        for (int m = 1; m < 16; m <<= 1) {
            p0 += __shfl_xor(p0, m); p1 += __shfl_xor(p1, m);
            p2 += __shfl_xor(p2, m); p3 += __shfl_xor(p3, m);
        }
        if (lq == 0) {
            int rowb = mt * 16 + quad * 4;
            pbuf[w * FMR + rowb + 0] = p0; pbuf[w * FMR + rowb + 1] = p1;
            pbuf[w * FMR + rowb + 2] = p2; pbuf[w * FMR + rowb + 3] = p3;
        }
    }
    __syncthreads();
    const int n = w & 1, lh = w >> 1;
    float att;
    {
        float s = -3.0e38f;
        if (lane < HL) {
            int gr = n * HL + lane;
            s = pbuf[gr] + pbuf[FMR + gr] + pbuf[2 * FMR + gr] + pbuf[3 * FMR + gr];
        }
        float mx = s;
        #pragma unroll
        for (int m = 1; m < 64; m <<= 1) mx = fmaxf(mx, __shfl_xor(mx, m));
        float e = (lane < HL) ? __expf(s - mx) : 0.f;
        float sm = e;
        #pragma unroll
        for (int m = 1; m < 64; m <<= 1) sm += __shfl_xor(sm, m);
        att = e / sm;
    }
    {
        float o = 0.f;
        const int lb = lh * 25;
        #pragma unroll
        for (int i = 0; i < 25; ++i) {
            int l = lb + i;
            float av = __shfl(att, l);
            o = fmaf(av, (float)xs[(n * HL + l) * FXSS + lane], o);
        }
        float* op = (float*)&xs[(100 + w) * FXSS + DD];
        op[lane] = o;
    }
    __syncthreads();
    if (w < 2) {
        const float* p0 = (const float*)&xs[(100 + w) * FXSS + DD];
        const float* p1 = (const float*)&xs[(100 + w + 2) * FXSS + DD];
        out[(size_t)(n0 + w) * DD + lane] = p0[lane] + p1[lane];
    }
}

// ================================ host ==================================
extern "C" void kernel_launch(void* const* d_in, const int* in_sizes, int n_in,
                              void* d_out, int out_size, void* d_ws, size_t ws_size,
                              hipStream_t stream) {
    const int*   nodes = (const int*)d_in[0];
    const int*   hva   = (const int*)d_in[1];
    const int*   haf   = (const int*)d_in[2];
    const float* v2e   = (const float*)d_in[3];
    const float* a2e   = (const float*)d_in[4];
    const float* f2e   = (const float*)d_in[5];
    const float* W1    = (const float*)d_in[6];
    const float* b1    = (const float*)d_in[7];
    const float* W2    = (const float*)d_in[8];
    const float* b2    = (const float*)d_in[9];
    const float* w3    = (const float*)d_in[10];
    // d_in[11] = b3: softmax shift-invariant — unused.
    float* out = (float*)d_out;

    const int N  = in_sizes[0];            // 8192
    const int nA = in_sizes[4] / DD;       // 100000
    const int nF = in_sizes[5] / DD;       // 100000

    size_t offA2 = 0;
    size_t offF2 = (offA2 + (size_t)nA * DD * 2 + 255) & ~(size_t)255;
    size_t offE  = (offF2 + (size_t)nF * DD * 2 + 255) & ~(size_t)255;
    size_t offBA = (offE  + (size_t)nA * DD * 2 + 255) & ~(size_t)255;
    size_t offWF = (offBA + (size_t)N * DD * 2 + 255) & ~(size_t)255;
    size_t offSC = offWF + 8 * 64 * 8 * 2;
    size_t need  = offSC + 128 * 4;

    if (ws_size >= need) {
        _Float16* A2  = (_Float16*)((char*)d_ws + offA2);
        _Float16* F2  = (_Float16*)((char*)d_ws + offF2);
        _Float16* E16 = (_Float16*)((char*)d_ws + offE);
        _Float16* ba  = (_Float16*)((char*)d_ws + offBA);
        _Float16* w2f = (_Float16*)((char*)d_ws + offWF);
        float*    wsc = (float*)((char*)d_ws + offSC);

        const int GAF = 448;               // grid-stride blocks per table
        const int GB  = (N + 63) / 64;
        prep_all_kernel<<<2 * GAF + GB + 1, 256, 0, stream>>>(
            nodes, v2e, a2e, f2e, W1, b1, W2, b2, w3,
            A2, F2, E16, ba, w2f, wsc, nA, nF, N, GAF, GB);
        va_main_kernel<<<(N + 3) / 4, 256, 0, stream>>>(
            hva, haf, A2, F2, E16, ba, w2f, wsc, out, N);
    } else {
        // workspace too small for precompute path — proven R6 fallback (33 KB)
        __bf16* wf  = (__bf16*)d_ws;
        float*  wsc = (float*)((char*)d_ws + 256 * 64 * 2);
        fb_prep_kernel<<<1, 256, 0, stream>>>(W1, W2, w3, b1, b2, wf, wsc);
        fb_agg_kernel<<<N / 2, 256, 0, stream>>>(nodes, hva, haf, v2e, a2e, f2e,
                                                 wf, wsc, out);
    }
}

// Round 4
// 147.989 us; speedup vs baseline: 1.1106x; 1.1106x over previous
//
#include <hip/hip_runtime.h>
#include <hip/hip_bf16.h>

typedef __bf16    bf16x8 __attribute__((ext_vector_type(8)));
typedef __bf16    bf16x4 __attribute__((ext_vector_type(4)));
typedef _Float16  f16x8  __attribute__((ext_vector_type(8)));
typedef _Float16  f16x4  __attribute__((ext_vector_type(4)));
typedef float     f32x4  __attribute__((ext_vector_type(4)));

#define HL 50
#define DD 64

// ============================ ALGORITHM =================================
// h1 = relu(A2[va] + F2[af] + ba[node]) with A2 = f16(a2e@W1[0:64]),
// F2 = f16(f2e@W1[128:192]), ba = f16(b1 + rep@W1[64:128]).
// R11: AE table merges A2 and E16 per attr row (256 B: [0:64)=A2 half,
// [64:128)=f16(a2e) half) so the post-softmax E-gather is L2-hot from the
// pre-GEMM A2 fetch.  Prep A/F branch = grid-stride DEPTH-2 pipelined
// tiles (ping-pong reg buffers, statically named).  Main = R8 wave-per-node
// with launch_bounds(256,4) — the proven <40.5us shape (R3's (256,6)
// shrank VGPR to 40 and serialized the gather burst: +6us).

// ---- fused prep: [0,GAF) A-tiles | [GAF,2GAF) F-tiles | bias | frags
__global__ __launch_bounds__(256, 4) void prep_all_kernel(
    const int*   __restrict__ nodes,
    const float* __restrict__ v2e,
    const float* __restrict__ a2e,
    const float* __restrict__ f2e,
    const float* __restrict__ W1,
    const float* __restrict__ b1,
    const float* __restrict__ W2,
    const float* __restrict__ b2,
    const float* __restrict__ w3,
    _Float16* __restrict__ AE, _Float16* __restrict__ F2,
    _Float16* __restrict__ ba16,
    _Float16* __restrict__ w2f, float* __restrict__ wsc,
    int nA, int nF, int N, int GAF, int GB)
{
    __shared__ __align__(16) _Float16 wlds[8 * 512];  // 8192 B: W1-part fragments
    __shared__ __align__(16) _Float16 es[64 * 72];    // 9216 B
    const int tid  = threadIdx.x;
    const int w    = tid >> 6, lane = tid & 63;
    const int lq   = lane & 15, quad = lane >> 4;
    const int bid  = blockIdx.x;

    if (bid < 2 * GAF) {
        // ==== embed transform: grid-stride tiles, DEPTH-2 pipeline ====
        const bool  isA    = (bid < GAF);
        const int   t0     = isA ? bid : bid - GAF;
        const int   nrows  = isA ? nA : nF;
        const int   NT     = (nrows + 63) >> 6;
        const int   dstride= isA ? 128 : 64;
        const float* src   = isA ? a2e : f2e;
        const float* Wp    = isA ? W1 : (W1 + 128 * DD);
        _Float16*   dst    = isA ? AE : F2;
        _Float16*   ws_    = &es[w * 16 * 72];         // wave-private slice

        // tile loader: 16 rows/wave as 4x float4 per lane
        auto loadtile = [&](int tb, float4 (&vv)[4], int (&gg)[4]) {
            const int r0w = tb * 64 + w * 16;
            #pragma unroll
            for (int i = 0; i < 4; ++i) {
                int t = i * 64 + lane;
                int row = t >> 4, chunk = t & 15;
                int gr = r0w + row; if (gr >= nrows) gr = nrows - 1;
                gg[i] = gr;
                vv[i] = *(const float4*)(src + (size_t)gr * DD + chunk * 4);
            }
        };

        // process one tile; reissues its reg buffer with tile tbc+2*GAF
        auto proc = [&](int tbc, float4 (&vv)[4], int (&gg)[4]) {
            const int r0w = tbc * 64 + w * 16;
            // cvt -> wave-private LDS (+ free e_va half of AE for A)
            #pragma unroll
            for (int i = 0; i < 4; ++i) {
                int t = i * 64 + lane;
                int row = t >> 4, chunk = t & 15;
                f16x4 pk = {(_Float16)vv[i].x, (_Float16)vv[i].y,
                            (_Float16)vv[i].z, (_Float16)vv[i].w};
                *(f16x4*)&ws_[row * 72 + chunk * 4] = pk;
                if (isA)
                    *(f16x4*)(dst + (size_t)gg[i] * 128 + 64 + chunk * 4) = pk;
            }
            // issue tile tbc+2*GAF into the just-freed buffer (2-iter lead)
            const int tn2 = tbc + 2 * GAF;
            if (tn2 < NT) loadtile(tn2, vv, gg);

            // fragments + 8 MFMA (4 col-tiles x 2 K-steps), wave-local
            f16x8 afr[2];
            #pragma unroll
            for (int t = 0; t < 2; ++t)
                afr[t] = *(const f16x8*)&ws_[lq * 72 + t * 32 + quad * 8];
            f32x4 acc[4];
            #pragma unroll
            for (int ct = 0; ct < 4; ++ct) {
                acc[ct] = (f32x4){0.f, 0.f, 0.f, 0.f};
                #pragma unroll
                for (int t = 0; t < 2; ++t) {
                    f16x8 bfr = *(const f16x8*)&wlds[(size_t)(ct * 2 + t) * 512 + lane * 8];
                    acc[ct] = __builtin_amdgcn_mfma_f32_16x16x32_f16(afr[t], bfr, acc[ct], 0, 0, 0);
                }
            }

            // repack via wave-private LDS, then vectorized global store
            #pragma unroll
            for (int ct = 0; ct < 4; ++ct)
                #pragma unroll
                for (int r = 0; r < 4; ++r)
                    ws_[(quad * 4 + r) * 72 + ct * 16 + lq] = (_Float16)acc[ct][r];
            {
                int row = lane >> 2, g = lane & 3;
                int gr  = r0w + row;
                if (gr < nrows) {
                    f16x8 v0 = *(const f16x8*)&ws_[row * 72 + g * 16];
                    f16x8 v1 = *(const f16x8*)&ws_[row * 72 + g * 16 + 8];
                    *(f16x8*)(dst + (size_t)gr * dstride + g * 16)     = v0;
                    *(f16x8*)(dst + (size_t)gr * dstride + g * 16 + 8) = v1;
                }
            }
        };

        // stage W1-part into LDS in fragment layout (L2-hot reads)
        #pragma unroll
        for (int h = 0; h < 2; ++h) {
            int combo = w + 4 * h;            // = ct*2 + t, combos 0..7
            int ct = combo >> 1, t = combo & 1;
            f16x8 pk;
            #pragma unroll
            for (int j = 0; j < 8; ++j)
                pk[j] = (_Float16)Wp[(t * 32 + quad * 8 + j) * DD + ct * 16 + lq];
            *(f16x8*)&wlds[(size_t)combo * 512 + lane * 8] = pk;
        }

        // prologue: two tiles' loads in flight across the barrier
        int    tb = t0;
        float4 vA[4], vB[4];
        int    gA[4], gB[4];
        loadtile(tb, vA, gA);
        if (tb + GAF < NT) loadtile(tb + GAF, vB, gB);

        __syncthreads();   // [only barrier] wlds ready; ws_ is wave-private

        for (;;) {
            proc(tb, vA, gA);                 // ping
            tb += GAF; if (tb >= NT) break;
            proc(tb, vB, gB);                 // pong
            tb += GAF; if (tb >= NT) break;
        }
    } else if (bid < 2 * GAF + GB) {
        // ---- bias branch: ba16[n][c] = f16(b1[c] + rep_n . W1[64:128, c]) ----
        const int col = w * 16 + lq;
        const int n0 = (bid - 2 * GAF) * 64;
        #pragma unroll
        for (int i = 0; i < 4; ++i) {
            int t = i * 256 + tid;
            int row = t >> 4, q = t & 15;
            int gn = n0 + row; if (gn >= N) gn = N - 1;
            int idx = nodes[gn];
            float4 v = *(const float4*)(v2e + (size_t)idx * DD + q * 4);
            f16x4 pk = {(_Float16)v.x, (_Float16)v.y, (_Float16)v.z, (_Float16)v.w};
            *(f16x4*)&es[row * 72 + q * 4] = pk;
        }
        f16x8 bfr[2];
        #pragma unroll
        for (int t = 0; t < 2; ++t)
            #pragma unroll
            for (int j = 0; j < 8; ++j)
                bfr[t][j] = (_Float16)W1[(64 + t * 32 + quad * 8 + j) * DD + col];
        const float b1c = b1[col];
        __syncthreads();

        f32x4 acc[4];
        #pragma unroll
        for (int mt = 0; mt < 4; ++mt) acc[mt] = (f32x4){0.f, 0.f, 0.f, 0.f};
        #pragma unroll
        for (int t = 0; t < 2; ++t)
            #pragma unroll
            for (int mt = 0; mt < 4; ++mt) {
                f16x8 a = *(const f16x8*)&es[(mt * 16 + lq) * 72 + t * 32 + quad * 8];
                acc[mt] = __builtin_amdgcn_mfma_f32_16x16x32_f16(a, bfr[t], acc[mt], 0, 0, 0);
            }
        #pragma unroll
        for (int mt = 0; mt < 4; ++mt)
            #pragma unroll
            for (int r = 0; r < 4; ++r) {
                int gn = n0 + mt * 16 + quad * 4 + r;
                if (gn < N) ba16[(size_t)gn * DD + col] = (_Float16)(acc[mt][r] + b1c);
            }
    } else {
        // ---- frag branch: W2 B-fragments (f16) + scalars ----
        const int ln = tid & 63, c0 = tid >> 6;
        #pragma unroll
        for (int h = 0; h < 2; ++h) {
            int combo = c0 + 4 * h;          // = ct*2 + t
            int ct = combo >> 1, t = combo & 1;
            _Float16* d = w2f + ((size_t)combo * 64 + ln) * 8;
            #pragma unroll
            for (int j = 0; j < 8; ++j)
                d[j] = (_Float16)W2[(t * 32 + (ln >> 4) * 8 + j) * DD + ct * 16 + (ln & 15)];
        }
        if (tid < 64) { wsc[tid] = w3[tid]; wsc[64 + tid] = b2[tid]; }
    }
}

// ---- main: ONE NODE PER WAVE — no barriers, no LDS, in-register softmax ----
__global__ __launch_bounds__(256, 4) void va_main_kernel(
    const int*      __restrict__ hva,
    const int*      __restrict__ haf,
    const _Float16* __restrict__ AE,
    const _Float16* __restrict__ F2,
    const _Float16* __restrict__ ba16,
    const _Float16* __restrict__ w2f,
    const float*    __restrict__ wsc,
    float*          __restrict__ out, int Ntot)
{
    const int tid  = threadIdx.x;
    const int w    = tid >> 6;
    const int lane = tid & 63;
    const int lq   = lane & 15;
    const int quad = lane >> 4;
    const int node = blockIdx.x * 4 + w;
    if (node >= Ntot) return;

    const int* hb = hva + node * HL;
    const int* fb = haf + node * HL;
    const int lclamp = (lane < HL) ? lane : 0;
    const int iv  = hb[lclamp];                 // lane l holds hva[l]
    const int ifv = fb[lclamp];                 // lane l holds haf[l]

    // ---- node-uniform bias fragments ----
    f16x8 bag[2];
    #pragma unroll
    for (int t = 0; t < 2; ++t)
        bag[t] = *(const f16x8*)(ba16 + (size_t)node * DD + t * 32 + quad * 8);

    // ---- gather A2/F2 fragments for all 4 row-tiles (burst issue) ----
    f16x8 a2g[4][2], f2g[4][2];
    #pragma unroll
    for (int mt = 0; mt < 4; ++mt) {
        const int row = mt * 16 + lq;
        const int ia  = __shfl(iv,  row);
        const int ifm = __shfl(ifv, row);
        const bool valid = (row < HL);          // compile-time true for mt<3
        #pragma unroll
        for (int t = 0; t < 2; ++t) {
            if (valid) {
                a2g[mt][t] = *(const f16x8*)(AE + (size_t)ia  * 128 + t * 32 + quad * 8);
                f2g[mt][t] = *(const f16x8*)(F2 + (size_t)ifm * DD  + t * 32 + quad * 8);
            }
        }
    }

    // ---- h1 = relu(A2 + F2 + ba), invalid rows forced to 0 ----
    f16x8 h1f[4][2];
    #pragma unroll
    for (int mt = 0; mt < 4; ++mt) {
        const bool valid = (mt * 16 + lq) < HL;
        #pragma unroll
        for (int t = 0; t < 2; ++t) {
            f16x8 h = a2g[mt][t] + f2g[mt][t] + bag[t];
            #pragma unroll
            for (int j = 0; j < 8; ++j)
                h1f[mt][t][j] = (valid && h[j] > (_Float16)0.f) ? h[j] : (_Float16)0.f;
        }
    }

    // ---- GEMM2 (4 row-tiles x 4 col-tiles x 2 K) + score partials ----
    float sc[4][4];
    #pragma unroll
    for (int mt = 0; mt < 4; ++mt)
        #pragma unroll
        for (int r = 0; r < 4; ++r) sc[mt][r] = 0.f;

    #pragma unroll
    for (int ct = 0; ct < 4; ++ct) {
        const float b2c = wsc[64 + ct * 16 + lq];
        const float w3c = wsc[ct * 16 + lq];
        f16x8 bfr[2];
        #pragma unroll
        for (int t = 0; t < 2; ++t)
            bfr[t] = *(const f16x8*)(w2f + ((size_t)(ct * 2 + t) * 64 + lane) * 8);
        #pragma unroll
        for (int mt = 0; mt < 4; ++mt) {
            f32x4 acc = {b2c, b2c, b2c, b2c};
            #pragma unroll
            for (int t = 0; t < 2; ++t)
                acc = __builtin_amdgcn_mfma_f32_16x16x32_f16(h1f[mt][t], bfr[t], acc, 0, 0, 0);
            #pragma unroll
            for (int r = 0; r < 4; ++r)
                sc[mt][r] = fmaf(fmaxf(acc[r], 0.f), w3c, sc[mt][r]);
        }
    }

    // ---- reduce scores over lq (each lane then holds its quad's 16 rows) ----
    #pragma unroll
    for (int mt = 0; mt < 4; ++mt)
        #pragma unroll
        for (int r = 0; r < 4; ++r)
            #pragma unroll
            for (int m = 1; m < 16; m <<= 1)
                sc[mt][r] += __shfl_xor(sc[mt][r], m);

    // ---- in-register softmax over 50 rows (row = mt*16 + quad*4 + r) ----
    #pragma unroll
    for (int r = 0; r < 4; ++r)
        if (48 + quad * 4 + r >= HL) sc[3][r] = -3.0e38f;   // rows 50..63

    float mx = sc[0][0];
    #pragma unroll
    for (int mt = 0; mt < 4; ++mt)
        #pragma unroll
        for (int r = 0; r < 4; ++r) mx = fmaxf(mx, sc[mt][r]);
    mx = fmaxf(mx, __shfl_xor(mx, 16));
    mx = fmaxf(mx, __shfl_xor(mx, 32));

    float sm = 0.f;
    #pragma unroll
    for (int mt = 0; mt < 4; ++mt)
        #pragma unroll
        for (int r = 0; r < 4; ++r) {
            sc[mt][r] = __expf(sc[mt][r] - mx);             // 0 for invalid rows
            sm += sc[mt][r];
        }
    sm += __shfl_xor(sm, 16);
    sm += __shfl_xor(sm, 32);
    const float inv = 1.f / sm;

    // ---- weighted e_va sum: AE e_va half is L2-hot from the A2 fetch ----
    float oa[4] = {0.f, 0.f, 0.f, 0.f};
    #pragma unroll
    for (int l = 0; l < HL; ++l) {
        const int   srcl = ((l >> 2) & 3) << 4;             // lane with quad=(l>>2)&3
        const float av   = __shfl(sc[l >> 4][l & 3], srcl);
        const int   idx  = __builtin_amdgcn_readlane(iv, l); // wave-uniform -> SGPR base
        oa[l & 3] = fmaf(av, (float)AE[(size_t)idx * 128 + 64 + lane], oa[l & 3]);
    }
    out[(size_t)node * DD + lane] = ((oa[0] + oa[1]) + (oa[2] + oa[3])) * inv;
}

// ======================= FALLBACK (proven R6 path) ======================
#define FMR  112
#define FMT  7
#define FXSS 136

__global__ __launch_bounds__(256) void fb_prep_kernel(
    const float* __restrict__ W1, const float* __restrict__ W2,
    const float* __restrict__ w3, const float* __restrict__ b1,
    const float* __restrict__ b2,
    __bf16* __restrict__ wf, float* __restrict__ wsc)
{
    const int tid  = threadIdx.x;
    const int quad = tid >> 6;
    const int col  = tid & 63;
    __bf16* dst = wf + tid * 64;
    #pragma unroll
    for (int t = 0; t < 4; ++t)
        #pragma unroll
        for (int j = 0; j < 8; ++j) {
            int keff = t * 32 + quad * 8 + j;
            int krow = (keff < 64) ? keff : keff + 64;
            dst[t * 8 + j] = (__bf16)W1[krow * 64 + col];
        }
    #pragma unroll
    for (int t = 0; t < 2; ++t)
        #pragma unroll
        for (int j = 0; j < 8; ++j) {
            dst[32 + t * 8 + j] = (__bf16)W1[(64 + t * 32 + quad * 8 + j) * 64 + col];
            dst[48 + t * 8 + j] = (__bf16)W2[(t * 32 + quad * 8 + j) * 64 + col];
        }
    if (tid < 64) {
        wsc[tid] = w3[tid]; wsc[64 + tid] = b1[tid]; wsc[128 + tid] = b2[tid];
    }
}

__global__ __launch_bounds__(256, 5) void fb_agg_kernel(
    const int* __restrict__ nodes, const int* __restrict__ hva,
    const int* __restrict__ haf, const float* __restrict__ v2e,
    const float* __restrict__ a2e, const float* __restrict__ f2e,
    const __bf16* __restrict__ wf, const float* __restrict__ wsc,
    float* __restrict__ out)
{
    __shared__ __bf16 xs[FMR * FXSS];
    __shared__ float  pbuf[4 * FMR];
    const int tid = threadIdx.x;
    const int w = tid >> 6, lane = tid & 63, lq = lane & 15, quad = lane >> 4;
    const int col = w * 16 + lq;
    const int n0 = blockIdx.x * 2;
    {
        const int* hb = hva + n0 * HL;
        const int* fb = haf + n0 * HL;
        #pragma unroll
        for (int i = 0; i < 13; ++i) {
            int t = i * 256 + tid;
            if (t < 2 * HL * 2 * 16) {
                int r = t >> 4, q = t & 15;
                bool va = (r < 2 * HL);
                int gr = va ? r : r - 2 * HL;
                int idx = va ? hb[gr] : fb[gr];
                const float* src = (va ? a2e : f2e) + (size_t)idx * DD + q * 4;
                float4 v = *(const float4*)src;
                bf16x4 pk = {(__bf16)v.x, (__bf16)v.y, (__bf16)v.z, (__bf16)v.w};
                *(bf16x4*)&xs[gr * FXSS + (va ? 0 : DD) + q * 4] = pk;
            }
        }
    }
    bf16x8 repf[2];
    #pragma unroll
    for (int t = 0; t < 2; ++t)
        #pragma unroll
        for (int j = 0; j < 8; ++j) repf[t][j] = (__bf16)0.f;
    if (lq < 2) {
        int nd = nodes[n0 + lq];
        const float* rp = v2e + (size_t)nd * DD;
        #pragma unroll
        for (int t = 0; t < 2; ++t) {
            float4 v0 = *(const float4*)(rp + t * 32 + quad * 8);
            float4 v1 = *(const float4*)(rp + t * 32 + quad * 8 + 4);
            repf[t] = (bf16x8){(__bf16)v0.x, (__bf16)v0.y, (__bf16)v0.z, (__bf16)v0.w,
                               (__bf16)v1.x, (__bf16)v1.y, (__bf16)v1.z, (__bf16)v1.w};
        }
    }
    const __bf16* fbp = wf + (size_t)(quad * 64 + col) * 64;
    bf16x8 b1f[4], b1u[2], b2f[2];
    #pragma unroll
    for (int t = 0; t < 4; ++t) b1f[t] = *(const bf16x8*)(fbp + t * 8);
    #pragma unroll
    for (int t = 0; t < 2; ++t) {
        b1u[t] = *(const bf16x8*)(fbp + 32 + t * 8);
        b2f[t] = *(const bf16x8*)(fbp + 48 + t * 8);
    }
    const float w3c = wsc[col];
    const float b1c = wsc[64 + col];
    const float b2c = wsc[128 + col];
    f32x4 rb = {0.f, 0.f, 0.f, 0.f};
    #pragma unroll
    for (int t = 0; t < 2; ++t)
        rb = __builtin_amdgcn_mfma_f32_16x16x32_bf16(repf[t], b1u[t], rb, 0, 0, 0);
    const float bias0 = __shfl(rb[0], lq) + b1c;
    const float bias1 = __shfl(rb[1], lq) + b1c;
    __syncthreads();
    f32x4 acc[FMT];
    #pragma unroll
    for (int mt = 0; mt < FMT; ++mt)
        #pragma unroll
        for (int r = 0; r < 4; ++r) {
            int gr = mt * 16 + quad * 4 + r;
            acc[mt][r] = (gr >= HL) ? bias1 : bias0;
        }
    #pragma unroll
    for (int t = 0; t < 4; ++t)
        #pragma unroll
        for (int mt = 0; mt < FMT; ++mt) {
            bf16x8 a = *(const bf16x8*)&xs[(mt * 16 + lq) * FXSS + t * 32 + quad * 8];
            acc[mt] = __builtin_amdgcn_mfma_f32_16x16x32_bf16(a, b1f[t], acc[mt], 0, 0, 0);
        }
    __syncthreads();
    #pragma unroll
    for (int mt = 0; mt < FMT; ++mt)
        #pragma unroll
        for (int r = 0; r < 4; ++r) {
            int gr = mt * 16 + quad * 4 + r;
            xs[gr * FXSS + DD + col] = (__bf16)fmaxf(acc[mt][r], 0.f);
        }
    __syncthreads();
    f32x4 a2[FMT];
    #pragma unroll
    for (int mt = 0; mt < FMT; ++mt) a2[mt] = (f32x4){b2c, b2c, b2c, b2c};
    #pragma unroll
    for (int t = 0; t < 2; ++t)
        #pragma unroll
        for (int mt = 0; mt < FMT; ++mt) {
            bf16x8 a = *(const bf16x8*)&xs[(mt * 16 + lq) * FXSS + DD + t * 32 + quad * 8];
            a2[mt] = __builtin_amdgcn_mfma_f32_16x16x32_bf16(a, b2f[t], a2[mt], 0, 0, 0);
        }
    #pragma unroll
    for (int mt = 0; mt < FMT; ++mt) {
        float p0 = fmaxf(a2[mt][0], 0.f) * w3c;
        float p1 = fmaxf(a2[mt][1], 0.f) * w3c;
        float p2 = fmaxf(a2[mt][2], 0.f) * w3c;
        float p3 = fmaxf(a2[mt][3], 0.f) * w3c;
        #pragma unroll
        for (int m = 1; m < 16; m <<= 1) {
            p0 += __shfl_xor(p0, m); p1 += __shfl_xor(p1, m);
            p2 += __shfl_xor(p2, m); p3 += __shfl_xor(p3, m);
        }
        if (lq == 0) {
            int rowb = mt * 16 + quad * 4;
            pbuf[w * FMR + rowb + 0] = p0; pbuf[w * FMR + rowb + 1] = p1;
            pbuf[w * FMR + rowb + 2] = p2; pbuf[w * FMR + rowb + 3] = p3;
        }
    }
    __syncthreads();
    const int n = w & 1, lh = w >> 1;
    float att;
    {
        float s = -3.0e38f;
        if (lane < HL) {
            int gr = n * HL + lane;
            s = pbuf[gr] + pbuf[FMR + gr] + pbuf[2 * FMR + gr] + pbuf[3 * FMR + gr];
        }
        float mx = s;
        #pragma unroll
        for (int m = 1; m < 64; m <<= 1) mx = fmaxf(mx, __shfl_xor(mx, m));
        float e = (lane < HL) ? __expf(s - mx) : 0.f;
        float sm = e;
        #pragma unroll
        for (int m = 1; m < 64; m <<= 1) sm += __shfl_xor(sm, m);
        att = e / sm;
    }
    {
        float o = 0.f;
        const int lb = lh * 25;
        #pragma unroll
        for (int i = 0; i < 25; ++i) {
            int l = lb + i;
            float av = __shfl(att, l);
            o = fmaf(av, (float)xs[(n * HL + l) * FXSS + lane], o);
        }
        float* op = (float*)&xs[(100 + w) * FXSS + DD];
        op[lane] = o;
    }
    __syncthreads();
    if (w < 2) {
        const float* p0 = (const float*)&xs[(100 + w) * FXSS + DD];
        const float* p1 = (const float*)&xs[(100 + w + 2) * FXSS + DD];
        out[(size_t)(n0 + w) * DD + lane] = p0[lane] + p1[lane];
    }
}

// ================================ host ==================================
extern "C" void kernel_launch(void* const* d_in, const int* in_sizes, int n_in,
                              void* d_out, int out_size, void* d_ws, size_t ws_size,
                              hipStream_t stream) {
    const int*   nodes = (const int*)d_in[0];
    const int*   hva   = (const int*)d_in[1];
    const int*   haf   = (const int*)d_in[2];
    const float* v2e   = (const float*)d_in[3];
    const float* a2e   = (const float*)d_in[4];
    const float* f2e   = (const float*)d_in[5];
    const float* W1    = (const float*)d_in[6];
    const float* b1    = (const float*)d_in[7];
    const float* W2    = (const float*)d_in[8];
    const float* b2    = (const float*)d_in[9];
    const float* w3    = (const float*)d_in[10];
    // d_in[11] = b3: softmax shift-invariant — unused.
    float* out = (float*)d_out;

    const int N  = in_sizes[0];            // 8192
    const int nA = in_sizes[4] / DD;       // 100000
    const int nF = in_sizes[5] / DD;       // 100000

    size_t offAE = 0;                                     // nA x 128 f16
    size_t offF2 = (offAE + (size_t)nA * 128 * 2 + 255) & ~(size_t)255;
    size_t offBA = (offF2 + (size_t)nF * DD * 2 + 255) & ~(size_t)255;
    size_t offWF = (offBA + (size_t)N * DD * 2 + 255) & ~(size_t)255;
    size_t offSC = offWF + 8 * 64 * 8 * 2;
    size_t need  = offSC + 128 * 4;

    if (ws_size >= need) {
        _Float16* AE  = (_Float16*)((char*)d_ws + offAE);
        _Float16* F2  = (_Float16*)((char*)d_ws + offF2);
        _Float16* ba  = (_Float16*)((char*)d_ws + offBA);
        _Float16* w2f = (_Float16*)((char*)d_ws + offWF);
        float*    wsc = (float*)((char*)d_ws + offSC);

        const int GAF = 320;               // grid-stride blocks per table
        const int GB  = (N + 63) / 64;
        prep_all_kernel<<<2 * GAF + GB + 1, 256, 0, stream>>>(
            nodes, v2e, a2e, f2e, W1, b1, W2, b2, w3,
            AE, F2, ba, w2f, wsc, nA, nF, N, GAF, GB);
        va_main_kernel<<<(N + 3) / 4, 256, 0, stream>>>(
            hva, haf, AE, F2, ba, w2f, wsc, out, N);
    } else {
        // workspace too small for precompute path — proven R6 fallback (33 KB)
        __bf16* wf  = (__bf16*)d_ws;
        float*  wsc = (float*)((char*)d_ws + 256 * 64 * 2);
        fb_prep_kernel<<<1, 256, 0, stream>>>(W1, W2, w3, b1, b2, wf, wsc);
        fb_agg_kernel<<<N / 2, 256, 0, stream>>>(nodes, hva, haf, v2e, a2e, f2e,
                                                 wf, wsc, out);
    }
}